// Round 1
// baseline (371.762 us; speedup 1.0000x reference)
//
#include <hip/hip_runtime.h>
#include <hip/hip_bf16.h>

typedef unsigned short u16;
typedef unsigned int u32;

typedef __bf16 bf16x8 __attribute__((ext_vector_type(8)));
typedef float f32x4 __attribute__((ext_vector_type(4)));

// bf16 round-to-nearest-even from f32
__device__ __forceinline__ u16 f2bf(float f) {
    u32 u = __float_as_uint(f);
    u32 r = (u + 0x7fffu + ((u >> 16) & 1u)) >> 16;
    return (u16)r;
}

// ---------------- Kernel A: normalize t_feat rows -> bf16 ----------------
// grid: 512 blocks (one per row c), block: 64 threads (1 wave)
__global__ void tnorm_kernel(const float* __restrict__ t_feat,
                             u16* __restrict__ tn,
                             const int* __restrict__ splitp) {
    const int row  = blockIdx.x;
    const int lane = threadIdx.x;  // 0..63, each handles 8 elems
    const float* rp = t_feat + (size_t)row * 512 + lane * 8;
    float4 x0 = *reinterpret_cast<const float4*>(rp);
    float4 x1 = *reinterpret_cast<const float4*>(rp + 4);
    float s = x0.x*x0.x + x0.y*x0.y + x0.z*x0.z + x0.w*x0.w
            + x1.x*x1.x + x1.y*x1.y + x1.z*x1.z + x1.w*x1.w;
#pragma unroll
    for (int off = 32; off > 0; off >>= 1) s += __shfl_xor(s, off, 64);
    float inv = 1.0f;
    if (*splitp == 1) inv = 1.0f / fmaxf(sqrtf(s), 1e-12f);
    u32 p0 = (u32)f2bf(x0.x*inv) | ((u32)f2bf(x0.y*inv) << 16);
    u32 p1 = (u32)f2bf(x0.z*inv) | ((u32)f2bf(x0.w*inv) << 16);
    u32 p2 = (u32)f2bf(x1.x*inv) | ((u32)f2bf(x1.y*inv) << 16);
    u32 p3 = (u32)f2bf(x1.z*inv) | ((u32)f2bf(x1.w*inv) << 16);
    uint4 packed; packed.x = p0; packed.y = p1; packed.z = p2; packed.w = p3;
    reinterpret_cast<uint4*>(tn)[row * 64 + lane] = packed;
}

// ---------------- Kernel B: per-(b,t) normalized mean over n -> bf16 ------
// grid: (t=256, b=32), block: 256 threads = 4 waves; wave w covers n = w+4*nn
__global__ void vmean_kernel(const float* __restrict__ v,
                             u16* __restrict__ vm,
                             const int* __restrict__ splitp) {
    const int t    = blockIdx.x;   // 0..255
    const int b    = blockIdx.y;   // 0..31
    const int tid  = threadIdx.x;  // 0..255
    const int w    = tid >> 6;     // wave 0..3
    const int lane = tid & 63;
    const int split = *splitp;
    __shared__ float lds[4 * 512];

    float acc[8];
#pragma unroll
    for (int i = 0; i < 8; i++) acc[i] = 0.f;

#pragma unroll
    for (int nn = 0; nn < 4; nn++) {
        const int n = w + nn * 4;
        const float* row = v + ((((size_t)b * 16 + n) * 256 + t) * 512) + lane * 8;
        float4 x0 = *reinterpret_cast<const float4*>(row);
        float4 x1 = *reinterpret_cast<const float4*>(row + 4);
        float s = x0.x*x0.x + x0.y*x0.y + x0.z*x0.z + x0.w*x0.w
                + x1.x*x1.x + x1.y*x1.y + x1.z*x1.z + x1.w*x1.w;
#pragma unroll
        for (int off = 32; off > 0; off >>= 1) s += __shfl_xor(s, off, 64);
        float inv = 1.0f;
        if (split == 1) inv = 1.0f / fmaxf(sqrtf(s), 1e-12f);
        acc[0] += x0.x * inv; acc[1] += x0.y * inv;
        acc[2] += x0.z * inv; acc[3] += x0.w * inv;
        acc[4] += x1.x * inv; acc[5] += x1.y * inv;
        acc[6] += x1.z * inv; acc[7] += x1.w * inv;
    }
    // cross-wave combine via LDS
#pragma unroll
    for (int i = 0; i < 8; i += 2) {
        float2 p; p.x = acc[i]; p.y = acc[i + 1];
        *reinterpret_cast<float2*>(&lds[w * 512 + lane * 8 + i]) = p;
    }
    __syncthreads();
    float2 r; r.x = 0.f; r.y = 0.f;
#pragma unroll
    for (int w2 = 0; w2 < 4; w2++) {
        float2 p = *reinterpret_cast<const float2*>(&lds[w2 * 512 + tid * 2]);
        r.x += p.x; r.y += p.y;
    }
    r.x *= (1.0f / 16.0f); r.y *= (1.0f / 16.0f);
    u32 packed = (u32)f2bf(r.x) | ((u32)f2bf(r.y) << 16);
    reinterpret_cast<u32*>(vm)[(((size_t)b * 256 + t) << 8) + tid] = packed;
}

// ---------------- Kernel C: out[b][c][t] = <t_norm[c,:], v_mean[b,t,:]>/tau
// grid: (cTiles=8, tTiles=4, b=32), block 256 = 4 waves; block tile 64(c)x64(t)
// wave computes 32x32 via 2x2 mfma_f32_16x16x32_bf16 frags; BK=64 LDS staging
__global__ __launch_bounds__(256) void gemm_kernel(const u16* __restrict__ tn,
                                                   const u16* __restrict__ vm,
                                                   float* __restrict__ out) {
    const int bx   = blockIdx.x;   // c tile
    const int by   = blockIdx.y;   // t tile
    const int b    = blockIdx.z;
    const int tid  = threadIdx.x;
    const int lane = tid & 63;
    const int wid  = tid >> 6;
    const int wm   = wid & 1;      // c dir
    const int wn   = wid >> 1;     // t dir
    const int quad = lane >> 4;
    const int l15  = lane & 15;

    // +8 bf16 pad per row -> 144B stride: <=2-way LDS conflicts (free)
    __shared__ u16 At[64 * 72];
    __shared__ u16 Bt[64 * 72];

    const int c0 = bx * 64, t0 = by * 64;
    f32x4 acc[2][2] = {};

    const int lrow = tid >> 3;        // 0..31 (staging row, two passes)
    const int lcol = (tid & 7) * 8;   // staging col in elements

    const uint4* gA = reinterpret_cast<const uint4*>(tn);
    const uint4* gB = reinterpret_cast<const uint4*>(vm) + (size_t)b * 256 * 64;

    for (int k0 = 0; k0 < 512; k0 += 64) {
#pragma unroll
        for (int it = 0; it < 2; it++) {
            int row = lrow + it * 32;
            uint4 av = gA[(c0 + row) * 64 + (k0 >> 3) + (tid & 7)];
            uint4 bv = gB[(t0 + row) * 64 + (k0 >> 3) + (tid & 7)];
            *reinterpret_cast<uint4*>(&At[row * 72 + lcol]) = av;
            *reinterpret_cast<uint4*>(&Bt[row * 72 + lcol]) = bv;
        }
        __syncthreads();
#pragma unroll
        for (int kk = 0; kk < 64; kk += 32) {
            bf16x8 af[2], bfr[2];
#pragma unroll
            for (int i = 0; i < 2; i++)
                af[i] = *reinterpret_cast<const bf16x8*>(
                    &At[(wm * 32 + i * 16 + l15) * 72 + kk + quad * 8]);
#pragma unroll
            for (int j = 0; j < 2; j++)
                bfr[j] = *reinterpret_cast<const bf16x8*>(
                    &Bt[(wn * 32 + j * 16 + l15) * 72 + kk + quad * 8]);
#pragma unroll
            for (int i = 0; i < 2; i++)
#pragma unroll
                for (int j = 0; j < 2; j++)
                    acc[i][j] = __builtin_amdgcn_mfma_f32_16x16x32_bf16(
                        af[i], bfr[j], acc[i][j], 0, 0, 0);
        }
        __syncthreads();
    }

    const float s = 1.0f / 0.07f;
    float* ob = out + (size_t)b * 131072;  // 512*256
#pragma unroll
    for (int i = 0; i < 2; i++)
#pragma unroll
        for (int j = 0; j < 2; j++)
#pragma unroll
            for (int r = 0; r < 4; r++) {
                int c = c0 + wm * 32 + i * 16 + quad * 4 + r;
                int t = t0 + wn * 32 + j * 16 + l15;
                ob[c * 256 + t] = acc[i][j][r] * s;
            }
}

extern "C" void kernel_launch(void* const* d_in, const int* in_sizes, int n_in,
                              void* d_out, int out_size, void* d_ws, size_t ws_size,
                              hipStream_t stream) {
    const float* v_feat = (const float*)d_in[0];   // (32,16,256,512)
    const float* t_feat = (const float*)d_in[1];   // (512,512)
    const int*   splitp = (const int*)d_in[2];
    float* out = (float*)d_out;                    // (32,512,256)

    u16* tn = (u16*)d_ws;                 // 512*512 bf16   = 512 KB
    u16* vm = tn + 512 * 512;             // 32*256*512 bf16 = 8 MB

    tnorm_kernel<<<dim3(512), dim3(64), 0, stream>>>(t_feat, tn, splitp);
    vmean_kernel<<<dim3(256, 32), dim3(256), 0, stream>>>(v_feat, vm, splitp);
    gemm_kernel<<<dim3(8, 4, 32), dim3(256), 0, stream>>>(tn, vm, out);
}